// Round 4
// baseline (201.163 us; speedup 1.0000x reference)
//
#include <hip/hip_runtime.h>

typedef __attribute__((ext_vector_type(4))) float f32x4;
typedef __attribute__((ext_vector_type(16))) float f32x16;
typedef __attribute__((ext_vector_type(8))) short bf16x8;

__device__ __forceinline__ unsigned short f2b(float f) {
  unsigned u = __float_as_uint(f);
  u = (u + 0x7FFFu + ((u >> 16) & 1u)) >> 16;
  return (unsigned short)u;
}

#define BAR() asm volatile("s_barrier" ::: "memory")
#define VMCNT(N) asm volatile("s_waitcnt vmcnt(" #N ")" ::: "memory")

// ---------------- K1: selector + skill-mix of LoRA params ----------------
__global__ void combine_kernel(const float* __restrict__ logits,   // [32][8]
                               const int*   __restrict__ tasks,    // [8]
                               const float* __restrict__ A,        // [8][2048][16]
                               const float* __restrict__ B,        // [8][16][2048]
                               unsigned short* __restrict__ Art,   // [8][16][2048]
                               unsigned short* __restrict__ Brt)   // [8][2048][16]
{
  int idx = blockIdx.x * 256 + threadIdx.x;
  int b = idx >> 11;
  int i = idx & 2047;
  if (b >= 8) return;
  int task = tasks[b];
  float p[8]; float s = 0.f;
  #pragma unroll
  for (int t = 0; t < 8; ++t) {
    float l = logits[task * 8 + t];
    float e = 1.f / (1.f + __expf(-l));
    p[t] = e; s += e;
  }
  float inv = 1.f / (s + 1e-12f);
  #pragma unroll
  for (int t = 0; t < 8; ++t) p[t] *= inv;

  float ar[16];
  #pragma unroll
  for (int r = 0; r < 16; ++r) ar[r] = 0.f;
  for (int t = 0; t < 8; ++t) {
    const float* ap = A + ((size_t)t * 2048 + i) * 16;
    float pt = p[t];
    #pragma unroll
    for (int r = 0; r < 16; ++r) ar[r] += pt * ap[r];
  }
  #pragma unroll
  for (int r = 0; r < 16; ++r)
    Art[((size_t)b * 16 + r) * 2048 + i] = f2b(ar[r]);

  float br[16];
  #pragma unroll
  for (int r = 0; r < 16; ++r) br[r] = 0.f;
  for (int t = 0; t < 8; ++t) {
    float pt = p[t];
    #pragma unroll
    for (int r = 0; r < 16; ++r) br[r] += pt * B[((size_t)t * 16 + r) * 2048 + i];
  }
  #pragma unroll
  for (int r = 0; r < 16; ++r)
    Brt[((size_t)b * 2048 + i) * 16 + r] = f2b(br[r] * 0.0625f);
}

// ---------------- K2: prep = {x f32->bf16 + xa = x@A_mix} ∪ {W f32->bf16} ----------------
__global__ void prep_kernel(const float* __restrict__ x,            // [16384][2048]
                            const unsigned short* __restrict__ Art, // [8][16][2048]
                            const float* __restrict__ W,            // [2048][2048]
                            unsigned short* __restrict__ Wb,        // [2048][2048]
                            unsigned short* __restrict__ xb,        // [16384][2048]
                            unsigned short* __restrict__ xa)        // [16384][16]
{
  __shared__ float red[4][16][16];
  int blk = blockIdx.x;
  int tid = threadIdx.x;
  if (blk >= 1024) {
    int idx0 = (blk - 1024) * 256 + tid;
    #pragma unroll
    for (int c = 0; c < 32; ++c) {
      size_t i = ((size_t)idx0 + (size_t)c * 32768) * 4;
      f32x4 v = *(const f32x4*)(W + i);
      ushort4 o;
      o.x = f2b(v.x); o.y = f2b(v.y); o.z = f2b(v.z); o.w = f2b(v.w);
      *(ushort4*)(Wb + i) = o;
    }
    return;
  }
  int lane = tid & 63, wv = tid >> 6;
  int lr = lane & 15, hi = lane >> 4;
  int rowbase = blk * 16;
  int batch = rowbase >> 11;
  int row = rowbase + lr;
  f32x4 acc; acc.x = 0.f; acc.y = 0.f; acc.z = 0.f; acc.w = 0.f;
  const float* xrow = x + (size_t)row * 2048 + wv * 512 + hi * 8;
  unsigned short* xbrow = xb + (size_t)row * 2048 + wv * 512 + hi * 8;
  const unsigned short* artrow = Art + ((size_t)batch * 16 + lr) * 2048 + wv * 512 + hi * 8;
  #pragma unroll
  for (int ks = 0; ks < 16; ++ks) {
    f32x4 v0 = *(const f32x4*)(xrow + ks * 32);
    f32x4 v1 = *(const f32x4*)(xrow + ks * 32 + 4);
    bf16x8 av;
    av[0] = (short)f2b(v0.x); av[1] = (short)f2b(v0.y);
    av[2] = (short)f2b(v0.z); av[3] = (short)f2b(v0.w);
    av[4] = (short)f2b(v1.x); av[5] = (short)f2b(v1.y);
    av[6] = (short)f2b(v1.z); av[7] = (short)f2b(v1.w);
    *(bf16x8*)(xbrow + ks * 32) = av;
    bf16x8 bv = *(const bf16x8*)(artrow + ks * 32);
    acc = __builtin_amdgcn_mfma_f32_16x16x32_bf16(av, bv, acc, 0, 0, 0);
  }
  #pragma unroll
  for (int j = 0; j < 4; ++j) red[wv][hi * 4 + j][lr] = acc[j];
  __syncthreads();
  int rr = tid >> 4, cc = tid & 15;
  float s = red[0][rr][cc] + red[1][rr][cc] + red[2][rr][cc] + red[3][rr][cc];
  xa[(size_t)(rowbase + rr) * 16 + cc] = f2b(s);
}

// ---------------- K3: 256x256 GEMM, 2-barrier K-loop, 32x32x16 MFMA + LoRA/bias ----------------
// 512 threads = 8 waves (2 wave-rows x 4 wave-cols). Per-wave output 128x64.
// LDS 128 KiB: buf d at d*65536; A tile [0,32768) rows=tile-row stride 128B;
//   B tile [32768,65536) rows=tile-col stride 128B. Direct row map (full-tile stage).
// T2 XOR swizzle both-sides: phys_colbyte = colbyte ^ ((row&7)<<4).
// K-loop: only 2 barriers per K-tile.
//   RD s0,s1 -> MM s0 -> RD s2 -> MM s1 -> RD s3 -> BAR(all reads done)
//   -> MM s2 -> STAGE kt+2 into cur buf -> MM s3 -> VMCNT(8)(lands kt+1) -> BAR.
// Register slots one-ahead => LDS transfer overlaps MFMA (no barrier between).
// Flight: staged tile issued mid-kt, landed end of kt+1 (~1 full K-tile > HBM lat).
__global__ __launch_bounds__(512, 2)
void gemm_kernel(const unsigned short* __restrict__ xb,  // [16384][2048] bf16
                 const unsigned short* __restrict__ Wb,  // [2048][2048]  bf16 (row = out col)
                 const float* __restrict__ bias,         // [2048]
                 const unsigned short* __restrict__ xa,  // [16384][16]   bf16
                 const unsigned short* __restrict__ Brt, // [8][2048][16] bf16 (pre-scaled 1/16)
                 float* __restrict__ out)                // [16384][2048] f32
{
  __shared__ __align__(16) char lds[131072];
  const int tid = threadIdx.x;
  const int lane = tid & 63;
  const int wv = tid >> 6;
  const int wr = wv >> 2, wc = wv & 3;
  const int rl = lane & 31, lh = lane >> 5;

  const int bid = blockIdx.x;
  const int swz = (bid & 7) * 64 + (bid >> 3);
  const int tm = swz >> 3, tn = swz & 7;
  const int rowbase = tm * 256, colbase = tn * 256;

  // staging geometry: thread stages row srow of each 64-row chunk, 16B at swizzled col
  const int srow = tid >> 3;
  const int scb_e = ((((tid & 7) * 16) ^ ((srow & 7) << 4)) >> 1);

  // read geometry: frag (row, ks): byte = row*128 + (((ks*2+lh) ^ (rl&7)) << 4)
  int koff[4];
  #pragma unroll
  for (int ks = 0; ks < 4; ++ks) koff[ks] = (((ks * 2 + lh) ^ (rl & 7)) << 4);
  int aro[4], bro[2];
  #pragma unroll
  for (int mf = 0; mf < 4; ++mf) aro[mf] = (wr * 128 + mf * 32 + rl) * 128;
  #pragma unroll
  for (int nf = 0; nf < 2; ++nf) bro[nf] = (wc * 64 + nf * 32 + rl) * 128;

#define GL16(LDSOFF, GPTR) \
  __builtin_amdgcn_global_load_lds((const __attribute__((address_space(1))) unsigned int*)(GPTR), \
      (__attribute__((address_space(3))) unsigned int*)(lds + (LDSOFF)), 16, 0, 0)

#define STAGE_TILE(DBUF, KOFFS) { \
  const unsigned short* ga_ = xb + (size_t)(rowbase + srow) * 2048 + (KOFFS) + scb_e; \
  const unsigned short* gb_ = Wb + (size_t)(colbase + srow) * 2048 + (KOFFS) + scb_e; \
  GL16((DBUF) * 65536 + tid * 16, ga_); \
  GL16((DBUF) * 65536 + 8192 + tid * 16, ga_ + 64 * 2048); \
  GL16((DBUF) * 65536 + 16384 + tid * 16, ga_ + 128 * 2048); \
  GL16((DBUF) * 65536 + 24576 + tid * 16, ga_ + 192 * 2048); \
  GL16((DBUF) * 65536 + 32768 + tid * 16, gb_); \
  GL16((DBUF) * 65536 + 40960 + tid * 16, gb_ + 64 * 2048); \
  GL16((DBUF) * 65536 + 49152 + tid * 16, gb_ + 128 * 2048); \
  GL16((DBUF) * 65536 + 57344 + tid * 16, gb_ + 192 * 2048); \
}

#define RD(S, AV, BV) { \
  _Pragma("unroll") \
  for (int mf = 0; mf < 4; ++mf) AV[mf] = *(const bf16x8*)(Ab + aro[mf] + koff[S]); \
  _Pragma("unroll") \
  for (int nf = 0; nf < 2; ++nf) BV[nf] = *(const bf16x8*)(Bb + bro[nf] + koff[S]); \
}

#define MM(AV, BV) \
  __builtin_amdgcn_s_setprio(1); \
  _Pragma("unroll") \
  for (int mf = 0; mf < 4; ++mf) \
    _Pragma("unroll") \
    for (int nf = 0; nf < 2; ++nf) \
      acc[mf][nf] = __builtin_amdgcn_mfma_f32_32x32x16_bf16(AV[mf], BV[nf], acc[mf][nf], 0, 0, 0); \
  __builtin_amdgcn_s_setprio(0);

  f32x16 acc[4][2];
  #pragma unroll
  for (int i = 0; i < 4; ++i)
    #pragma unroll
    for (int n = 0; n < 2; ++n)
      #pragma unroll
      for (int r = 0; r < 16; ++r) acc[i][n][r] = 0.f;

  bf16x8 av0[4], bv0[2], av1[4], bv1[2];

  // Prologue: stage kt0 -> buf0, kt1 -> buf1; VMCNT(8) lands kt0.
  STAGE_TILE(0, 0);
  STAGE_TILE(1, 64);
  VMCNT(8);
  BAR();

  for (int kt = 0; kt < 32; ++kt) {
    const int buf = kt & 1;
    const char* Ab = lds + buf * 65536;
    const char* Bb = Ab + 32768;

    RD(0, av0, bv0);
    RD(1, av1, bv1);
    MM(av0, bv0);
    RD(2, av0, bv0);
    MM(av1, bv1);
    RD(3, av1, bv1);
    BAR();                       // all waves done reading cur buf (WAR for stage below)
    MM(av0, bv0);
    if (kt < 30) STAGE_TILE(buf, (kt + 2) * 64);
    MM(av1, bv1);
    if (kt < 30) { VMCNT(8); }   // outstanding kt+1(8)+kt+2(8)=16 -> lands kt+1
    else if (kt == 30) { VMCNT(0); }
    BAR();
  }

  // ---- LoRA epilogue: exact-K MFMA (rank 16 == K of 32x32x16) ----
  const int batch = rowbase >> 11;
  bf16x8 la[4], lb[2];
  #pragma unroll
  for (int i = 0; i < 4; ++i)
    la[i] = *(const bf16x8*)(xa + (size_t)(rowbase + wr * 128 + i * 32 + rl) * 16 + lh * 8);
  #pragma unroll
  for (int n = 0; n < 2; ++n)
    lb[n] = *(const bf16x8*)(Brt + ((size_t)batch * 2048 + colbase + wc * 64 + n * 32 + rl) * 16 + lh * 8);
  #pragma unroll
  for (int i = 0; i < 4; ++i)
    #pragma unroll
    for (int n = 0; n < 2; ++n)
      acc[i][n] = __builtin_amdgcn_mfma_f32_32x32x16_bf16(la[i], lb[n], acc[i][n], 0, 0, 0);

  // ---- bias + store (32x32 C/D: col = lane&31, row = (r&3) + 8*(r>>2) + 4*lh) ----
  #pragma unroll
  for (int n = 0; n < 2; ++n) {
    int col = colbase + wc * 64 + n * 32 + rl;
    float bbv = bias[col];
    #pragma unroll
    for (int i = 0; i < 4; ++i) {
      int r0 = rowbase + wr * 128 + i * 32 + 4 * lh;
      #pragma unroll
      for (int r = 0; r < 16; ++r) {
        int row = r0 + (r & 3) + 8 * (r >> 2);
        out[(size_t)row * 2048 + col] = acc[i][n][r] + bbv;
      }
    }
  }
#undef GL16
#undef STAGE_TILE
#undef RD
#undef MM
}

extern "C" void kernel_launch(void* const* d_in, const int* in_sizes, int n_in,
                              void* d_out, int out_size, void* d_ws, size_t ws_size,
                              hipStream_t stream) {
  const float* x      = (const float*)d_in[0];   // [8][2048][2048]
  const float* W      = (const float*)d_in[1];   // [2048][2048]
  const float* bias   = (const float*)d_in[2];   // [2048]
  const float* logits = (const float*)d_in[3];   // [32][8]
  const float* A      = (const float*)d_in[4];   // [1][8][2048][16]
  const float* B      = (const float*)d_in[5];   // [1][8][16][2048]
  const int*   tasks  = (const int*)d_in[6];     // [8]
  float* out = (float*)d_out;

  char* ws = (char*)d_ws;
  unsigned short* xb  = (unsigned short*)(ws);                         // 67108864 B
  unsigned short* Wb  = (unsigned short*)(ws + 67108864);              //  8388608 B
  unsigned short* xa  = (unsigned short*)(ws + 67108864 + 8388608);    //   524288 B
  unsigned short* Art = (unsigned short*)(ws + 67108864 + 8388608 + 524288);
  unsigned short* Brt = (unsigned short*)(ws + 67108864 + 8388608 + 1048576);

  combine_kernel<<<64, 256, 0, stream>>>(logits, tasks, A, B, Art, Brt);
  prep_kernel<<<1152, 256, 0, stream>>>(x, Art, W, Wb, xb, xa);
  gemm_kernel<<<512, 512, 0, stream>>>(xb, Wb, bias, xa, Brt, out);
}